// Round 1
// baseline (248.617 us; speedup 1.0000x reference)
//
#include <hip/hip_runtime.h>
#include <stdint.h>

#define N_ACT 100000
#define B_ROWS 2048
#define NPAD 100352          // 3136 * 32
#define NC16 (NPAD / 16)     // 6272
#define NC32 (NPAD / 32)     // 3136
#define MC16 (B_ROWS / 16)   // 128
#define MBLK 16              // B / 128
#define NSPLIT 98
#define CPB (NC32 / NSPLIT)  // 32 n-chunks per block

typedef __attribute__((ext_vector_type(8))) short bf16x8;
typedef __attribute__((ext_vector_type(4))) float f32x4;

// ---- bf16 helpers (RNE via bit trick; no NaN inputs here) ----
static __device__ __forceinline__ unsigned short f2bf(float f) {
  unsigned u = __float_as_uint(f);
  u += 0x7fffu + ((u >> 16) & 1u);
  return (unsigned short)(u >> 16);
}
static __device__ __forceinline__ float bf2f(unsigned short h) {
  return __uint_as_float(((unsigned)h) << 16);
}
// split p into hi/lo bf16, packed (lo<<16)|hi
static __device__ __forceinline__ unsigned split_pack(float v) {
  unsigned short h = f2bf(v);
  unsigned short l = f2bf(v - bf2f(h));
  return ((unsigned)l << 16) | (unsigned)h;
}

// ---- prep: pack rows of a [rows x 64] fp32 matrix into hi/lo bf16 MFMA
// B/A-frags for 16x16x32: lane holds M[chunk*16 + (lane&15)][kh*32 + (lane>>4)*8 + j]
__global__ void prep_pack(const float* __restrict__ src, int nvalid,
                          bf16x8* __restrict__ dh, bf16x8* __restrict__ dl,
                          int nfrag) {
  int tid = blockIdx.x * 256 + threadIdx.x;
  if (tid >= nfrag * 64) return;
  int lane = tid & 63, fi = tid >> 6;
  int kh = fi & 1, nc = fi >> 1;
  int row = nc * 16 + (lane & 15);
  int k0 = kh * 32 + (lane >> 4) * 8;
  float v[8];
  if (row < nvalid) {
    const float4* p = (const float4*)(src + row * 64 + k0);
    float4 a = p[0], b = p[1];
    v[0] = a.x; v[1] = a.y; v[2] = a.z; v[3] = a.w;
    v[4] = b.x; v[5] = b.y; v[6] = b.z; v[7] = b.w;
  } else {
#pragma unroll
    for (int j = 0; j < 8; ++j) v[j] = 0.f;
  }
  bf16x8 hv, lv;
#pragma unroll
  for (int j = 0; j < 8; ++j) {
    unsigned short h = f2bf(v[j]);
    hv[j] = (short)h;
    lv[j] = (short)f2bf(v[j] - bf2f(h));
  }
  dh[tid] = hv;
  dl[tid] = lv;
}

// ---- prep: alpha [N x 16] -> B-frags for 2nd GEMM (k = n within chunk of 32)
// lane holds alpha[nc2*32 + (lane>>4)*8 + j][lane&15]
__global__ void prep_alpha(const float* __restrict__ alpha,
                           bf16x8* __restrict__ dh, bf16x8* __restrict__ dl) {
  int tid = blockIdx.x * 256 + threadIdx.x;  // exactly NC32*64 threads
  int lane = tid & 63, nc2 = tid >> 6;
  int f = lane & 15, q = lane >> 4;
  bf16x8 hv, lv;
#pragma unroll
  for (int j = 0; j < 8; ++j) {
    int n = nc2 * 32 + q * 8 + j;
    float v = (n < N_ACT) ? alpha[n * 16 + f] : 0.f;
    unsigned short h = f2bf(v);
    hv[j] = (short)h;
    lv[j] = (short)f2bf(v - bf2f(h));
  }
  dh[tid] = hv;
  dl[tid] = lv;
}

// ---- prep: dst[row] = -0.5 * ||src_row||^2 ; one wave per row, coalesced
__global__ void prep_sq(const float* __restrict__ src, float* __restrict__ dst,
                        int nvalid, int ntot) {
  int gw = (blockIdx.x * 256 + threadIdx.x) >> 6;
  int lane = threadIdx.x & 63;
  if (gw >= ntot) return;
  float s = 0.f;
  if (gw < nvalid) {
    float v = src[gw * 64 + lane];
    s = v * v;
  }
#pragma unroll
  for (int off = 32; off; off >>= 1) s += __shfl_xor(s, off, 64);
  if (lane == 0) dst[gw] = -0.5f * s;
}

// ---- main fused kernel: per wave 32 m-rows, n-chunks of 32, split-bf16 MFMA
__global__ __launch_bounds__(256) void rbf_main(
    const bf16x8* __restrict__ xph, const bf16x8* __restrict__ xpl,
    const bf16x8* __restrict__ aph, const bf16x8* __restrict__ apl,
    const bf16x8* __restrict__ zph, const bf16x8* __restrict__ zpl,
    const float* __restrict__ xs2, const float* __restrict__ zs2,
    float* __restrict__ out) {
  // per-wave private P tile: 32 rows (m) x 32 cols (n), packed (lo<<16|hi),
  // stride 36 dwords -> quad row-step = 144 dw = bank+16 -> worst 2-way (free)
  __shared__ unsigned int plds[4][32][36];
  const int lane = threadIdx.x & 63;
  const int w = threadIdx.x >> 6;
  const int q = lane >> 4, c = lane & 15;
  const int mc0 = blockIdx.x * 8 + w * 2;  // m-chunk16 index of mi=0

  // z fragments: [mi][kh][hi/lo], loaded once, reused across whole n-range
  bf16x8 zf[2][2][2];
#pragma unroll
  for (int mi = 0; mi < 2; ++mi)
#pragma unroll
    for (int kh = 0; kh < 2; ++kh) {
      int idx = ((mc0 + mi) * 2 + kh) * 64 + lane;
      zf[mi][kh][0] = zph[idx];
      zf[mi][kh][1] = zpl[idx];
    }
  // -0.5*||z_m||^2 for the 8 output rows this lane owns (C/D row = q*4+r)
  float zr[2][4];
#pragma unroll
  for (int mi = 0; mi < 2; ++mi)
#pragma unroll
    for (int r = 0; r < 4; ++r) zr[mi][r] = zs2[(mc0 + mi) * 16 + q * 4 + r];

  f32x4 oacc[2];
  oacc[0] = (f32x4){0.f, 0.f, 0.f, 0.f};
  oacc[1] = (f32x4){0.f, 0.f, 0.f, 0.f};

  const int nc2_0 = blockIdx.y * CPB;
  for (int it = 0; it < CPB; ++it) {
    const int nc2 = nc2_0 + it;
    // x fragments: [nh][kh][hi/lo]
    bf16x8 xf[2][2][2];
#pragma unroll
    for (int nh = 0; nh < 2; ++nh)
#pragma unroll
      for (int kh = 0; kh < 2; ++kh) {
        int idx = ((nc2 * 2 + nh) * 2 + kh) * 64 + lane;
        xf[nh][kh][0] = xph[idx];
        xf[nh][kh][1] = xpl[idx];
      }
    float x2[2];
    x2[0] = xs2[nc2 * 32 + c];
    x2[1] = xs2[nc2 * 32 + 16 + c];
    bf16x8 ah = aph[nc2 * 64 + lane];
    bf16x8 al = apl[nc2 * 64 + lane];

    // S = z . x^T with split-bf16 (hi*hi + hi*lo + lo*hi), K=64 in 2 halves
    f32x4 S[2][2];
#pragma unroll
    for (int mi = 0; mi < 2; ++mi)
#pragma unroll
      for (int nh = 0; nh < 2; ++nh) {
        f32x4 acc = (f32x4){0.f, 0.f, 0.f, 0.f};
#pragma unroll
        for (int kh = 0; kh < 2; ++kh) {
          acc = __builtin_amdgcn_mfma_f32_16x16x32_bf16(zf[mi][kh][0], xf[nh][kh][0], acc, 0, 0, 0);
          acc = __builtin_amdgcn_mfma_f32_16x16x32_bf16(zf[mi][kh][0], xf[nh][kh][1], acc, 0, 0, 0);
          acc = __builtin_amdgcn_mfma_f32_16x16x32_bf16(zf[mi][kh][1], xf[nh][kh][0], acc, 0, 0, 0);
        }
        S[mi][nh] = acc;
      }

    // epilogue: P = exp(S - 0.5||z||^2 - 0.5||x||^2), split hi/lo -> LDS
#pragma unroll
    for (int mi = 0; mi < 2; ++mi)
#pragma unroll
      for (int nh = 0; nh < 2; ++nh)
#pragma unroll
        for (int r = 0; r < 4; ++r) {
          float p = __expf(S[mi][nh][r] + zr[mi][r] + x2[nh]);
          plds[w][mi * 16 + q * 4 + r][nh * 16 + c] = split_pack(p);
        }

    // reload P in A-operand layout and do out += P @ alpha (split-bf16)
#pragma unroll
    for (int mi = 0; mi < 2; ++mi) {
      unsigned dw[8];
#pragma unroll
      for (int j = 0; j < 8; ++j) dw[j] = plds[w][mi * 16 + c][q * 8 + j];
      bf16x8 ph, pl;
#pragma unroll
      for (int j = 0; j < 8; ++j) {
        ph[j] = (short)(dw[j] & 0xffffu);
        pl[j] = (short)(dw[j] >> 16);
      }
      oacc[mi] = __builtin_amdgcn_mfma_f32_16x16x32_bf16(ph, ah, oacc[mi], 0, 0, 0);
      oacc[mi] = __builtin_amdgcn_mfma_f32_16x16x32_bf16(ph, al, oacc[mi], 0, 0, 0);
      oacc[mi] = __builtin_amdgcn_mfma_f32_16x16x32_bf16(pl, ah, oacc[mi], 0, 0, 0);
    }
  }

  // C/D layout: row(m) = q*4+r, col(f) = c ; accumulate across n-splits
#pragma unroll
  for (int mi = 0; mi < 2; ++mi)
#pragma unroll
    for (int r = 0; r < 4; ++r) {
      int m = blockIdx.x * 128 + w * 32 + mi * 16 + q * 4 + r;
      atomicAdd(&out[m * 16 + c], oacc[mi][r]);
    }
}

extern "C" void kernel_launch(void* const* d_in, const int* in_sizes, int n_in,
                              void* d_out, int out_size, void* d_ws, size_t ws_size,
                              hipStream_t stream) {
  const float* z = (const float*)d_in[0];
  const float* dataset = (const float*)d_in[1];
  const float* alpha = (const float*)d_in[2];
  float* out = (float*)d_out;
  char* ws = (char*)d_ws;

  // workspace layout (bytes): total ~33.05 MB
  bf16x8* xph = (bf16x8*)ws;                     // 2*6272*64 frags *16B = 12.85MB
  bf16x8* xpl = xph + NC16 * 2 * 64;             // +12.85MB
  bf16x8* aph = (bf16x8*)(ws + 25690112);        // 3136*64 frags
  bf16x8* apl = aph + NC32 * 64;
  bf16x8* zph = (bf16x8*)(ws + 32112640);
  bf16x8* zpl = zph + MC16 * 2 * 64;
  float* xs2 = (float*)(ws + 32636928);          // NPAD floats
  float* zs2 = (float*)(ws + 33038336);          // B floats

  hipMemsetAsync(d_out, 0, (size_t)out_size * sizeof(float), stream);
  prep_pack<<<dim3(NC16 * 2 * 64 / 256), dim3(256), 0, stream>>>(dataset, N_ACT, xph, xpl, NC16 * 2);
  prep_pack<<<dim3(MC16 * 2 * 64 / 256), dim3(256), 0, stream>>>(z, B_ROWS, zph, zpl, MC16 * 2);
  prep_alpha<<<dim3(NC32 * 64 / 256), dim3(256), 0, stream>>>(alpha, aph, apl);
  prep_sq<<<dim3(NPAD / 4), dim3(256), 0, stream>>>(dataset, xs2, N_ACT, NPAD);
  prep_sq<<<dim3(B_ROWS / 4), dim3(256), 0, stream>>>(z, zs2, B_ROWS, B_ROWS);
  rbf_main<<<dim3(MBLK, NSPLIT), dim3(256), 0, stream>>>(xph, xpl, aph, apl, zph, zpl, xs2, zs2, out);
}

// Round 2
// 193.285 us; speedup vs baseline: 1.2863x; 1.2863x over previous
//
#include <hip/hip_runtime.h>
#include <stdint.h>

#define N_ACT 100000
#define B_ROWS 2048
#define NPAD 100352          // 3136 * 32
#define NC16 (NPAD / 16)     // 6272
#define NC32 (NPAD / 32)     // 3136
#define MC16 (B_ROWS / 16)   // 128
#define MBLK 16              // B / 128
#define NSPLIT 196
#define CPB (NC32 / NSPLIT)  // 16 n-chunks per block

#define SCALE 1.2011224087864498f   // sqrt(log2(e)); z'.x' = log2e * z.x

typedef __attribute__((ext_vector_type(8))) short bf16x8;
typedef __attribute__((ext_vector_type(4))) float f32x4;

#if __has_builtin(__builtin_amdgcn_exp2f)
#define EXP2(x) __builtin_amdgcn_exp2f(x)
#else
#define EXP2(x) exp2f(x)
#endif

// pack hi16 of two fp32 bit-patterns: result = (u1.hi16 << 16) | u0.hi16
static __device__ __forceinline__ unsigned pack_hi16(unsigned u1, unsigned u0) {
#if __has_builtin(__builtin_amdgcn_perm)
  return __builtin_amdgcn_perm(u1, u0, 0x07060302u);
#else
  return (u1 & 0xffff0000u) | (u0 >> 16);
#endif
}

// ---- bf16 helpers (RNE) for prep ----
static __device__ __forceinline__ unsigned short f2bf(float f) {
  unsigned u = __float_as_uint(f);
  u += 0x7fffu + ((u >> 16) & 1u);
  return (unsigned short)(u >> 16);
}
static __device__ __forceinline__ float bf2f(unsigned short h) {
  return __uint_as_float(((unsigned)h) << 16);
}

// ---- prep: scale rows by SCALE, split into hi/lo bf16 MFMA frags (both kh
// halves), and compute sq[row] = -0.5*||scaled row||^2 = -0.5*log2e*||row||^2.
// One wave per 16-row chunk. Frag: lane(q,c) holds M[nc*16+c][kh*32+q*8+j].
__global__ void prep_pack_sq(const float* __restrict__ src, int nvalid, int nchunk,
                             bf16x8* __restrict__ dh, bf16x8* __restrict__ dl,
                             float* __restrict__ sq) {
  int wid = (blockIdx.x * 256 + threadIdx.x) >> 6;
  if (wid >= nchunk) return;
  int lane = threadIdx.x & 63;
  int q = lane >> 4, c = lane & 15;
  int row = wid * 16 + c;
  float v[2][8];
  if (row < nvalid) {
    const float4* p0 = (const float4*)(src + row * 64 + q * 8);
    const float4* p1 = (const float4*)(src + row * 64 + 32 + q * 8);
    float4 a = p0[0], b = p0[1], e = p1[0], f = p1[1];
    v[0][0] = a.x * SCALE; v[0][1] = a.y * SCALE; v[0][2] = a.z * SCALE; v[0][3] = a.w * SCALE;
    v[0][4] = b.x * SCALE; v[0][5] = b.y * SCALE; v[0][6] = b.z * SCALE; v[0][7] = b.w * SCALE;
    v[1][0] = e.x * SCALE; v[1][1] = e.y * SCALE; v[1][2] = e.z * SCALE; v[1][3] = e.w * SCALE;
    v[1][4] = f.x * SCALE; v[1][5] = f.y * SCALE; v[1][6] = f.z * SCALE; v[1][7] = f.w * SCALE;
  } else {
#pragma unroll
    for (int kh = 0; kh < 2; ++kh)
#pragma unroll
      for (int j = 0; j < 8; ++j) v[kh][j] = 0.f;
  }
  float s = 0.f;
#pragma unroll
  for (int kh = 0; kh < 2; ++kh)
#pragma unroll
    for (int j = 0; j < 8; ++j) s += v[kh][j] * v[kh][j];
  s += __shfl_xor(s, 16, 64);
  s += __shfl_xor(s, 32, 64);
#pragma unroll
  for (int kh = 0; kh < 2; ++kh) {
    bf16x8 hv, lv;
#pragma unroll
    for (int j = 0; j < 8; ++j) {
      unsigned short h = f2bf(v[kh][j]);
      hv[j] = (short)h;
      lv[j] = (short)f2bf(v[kh][j] - bf2f(h));
    }
    dh[(wid * 2 + kh) * 64 + lane] = hv;
    dl[(wid * 2 + kh) * 64 + lane] = lv;
  }
  if (lane < 16) sq[wid * 16 + c] = -0.5f * s;
}

// ---- prep: alpha [N x 16] -> B-frags for 2nd GEMM (k = n within chunk of 32)
// lane holds alpha[nc2*32 + (lane>>4)*8 + j][lane&15]; hi+lo split kept.
__global__ void prep_alpha(const float* __restrict__ alpha,
                           bf16x8* __restrict__ dh, bf16x8* __restrict__ dl) {
  int tid = blockIdx.x * 256 + threadIdx.x;  // exactly NC32*64 threads
  int lane = tid & 63, nc2 = tid >> 6;
  int f = lane & 15, q = lane >> 4;
  bf16x8 hv, lv;
#pragma unroll
  for (int j = 0; j < 8; ++j) {
    int n = nc2 * 32 + q * 8 + j;
    float v = (n < N_ACT) ? alpha[n * 16 + f] : 0.f;
    unsigned short h = f2bf(v);
    hv[j] = (short)h;
    lv[j] = (short)f2bf(v - bf2f(h));
  }
  dh[tid] = hv;
  dl[tid] = lv;
}

// ---- main fused kernel ----
// S^T tiles: mfma(A=x_frag, B=z_frag) -> D[row=n=q*4+r][col=m=c]; lane owns 4
// consecutive n -> pack bf16 pairs -> b32 LDS writes into row-major P[m][n];
// reload as A-frag via aligned ds_read_b128 (row stride 80B).
__global__ __launch_bounds__(256) void rbf_main(
    const bf16x8* __restrict__ xph, const bf16x8* __restrict__ xpl,
    const bf16x8* __restrict__ aph, const bf16x8* __restrict__ apl,
    const bf16x8* __restrict__ zph, const bf16x8* __restrict__ zpl,
    const float* __restrict__ xs2, const float* __restrict__ zs2,
    float* __restrict__ out) {
  __shared__ __align__(16) unsigned short plds[4][32][40];  // per-wave 32x32 bf16, stride 40
  const int lane = threadIdx.x & 63;
  const int w = threadIdx.x >> 6;
  const int q = lane >> 4, c = lane & 15;
  const int mc0 = blockIdx.x * 8 + w * 2;  // m-chunk16 index of mi=0

  // z fragments (B operand), loop-invariant
  bf16x8 zf[2][2][2];
#pragma unroll
  for (int mi = 0; mi < 2; ++mi)
#pragma unroll
    for (int kh = 0; kh < 2; ++kh) {
      int idx = ((mc0 + mi) * 2 + kh) * 64 + lane;
      zf[mi][kh][0] = zph[idx];
      zf[mi][kh][1] = zpl[idx];
    }

  f32x4 oacc[2];
  oacc[0] = (f32x4){0.f, 0.f, 0.f, 0.f};
  oacc[1] = (f32x4){0.f, 0.f, 0.f, 0.f};

  // LDS addresses: write dwords at row (w*32+mi*16+c), dword col nh*8+q*2+p
  unsigned* pw = (unsigned*)plds + ((w * 32 + c) * 20 + q * 2);

  const int nc2_0 = blockIdx.y * CPB;
  for (int it = 0; it < CPB; ++it) {
    const int nc2 = nc2_0 + it;
    // x fragments (A operand)
    bf16x8 xf[2][2][2];
#pragma unroll
    for (int nh = 0; nh < 2; ++nh)
#pragma unroll
      for (int kh = 0; kh < 2; ++kh) {
        int idx = ((nc2 * 2 + nh) * 2 + kh) * 64 + lane;
        xf[nh][kh][0] = xph[idx];
        xf[nh][kh][1] = xpl[idx];
      }
    // -0.5*log2e*||x_n||^2 for the 4 n-rows this lane owns, per nh: float4
    f32x4 xq[2];
#pragma unroll
    for (int nh = 0; nh < 2; ++nh) {
      const float4* xp = (const float4*)(xs2 + nc2 * 32 + nh * 16) + q;
      float4 t = *xp;
      xq[nh] = (f32x4){t.x, t.y, t.z, t.w};
    }
    bf16x8 ah = aph[nc2 * 64 + lane];
    bf16x8 al = apl[nc2 * 64 + lane];

    // S' = x'.z'^T - 0.5||x'||^2 (acc pre-initialized with xq); 3-term split
#pragma unroll
    for (int mi = 0; mi < 2; ++mi)
#pragma unroll
      for (int nh = 0; nh < 2; ++nh) {
        f32x4 acc = xq[nh];
#pragma unroll
        for (int kh = 0; kh < 2; ++kh) {
          acc = __builtin_amdgcn_mfma_f32_16x16x32_bf16(xf[nh][kh][0], zf[mi][kh][0], acc, 0, 0, 0);
          acc = __builtin_amdgcn_mfma_f32_16x16x32_bf16(xf[nh][kh][1], zf[mi][kh][0], acc, 0, 0, 0);
          acc = __builtin_amdgcn_mfma_f32_16x16x32_bf16(xf[nh][kh][0], zf[mi][kh][1], acc, 0, 0, 0);
        }
        // epilogue: P = 2^acc, round-half-up to bf16, pack pairs, one b32 write
#pragma unroll
        for (int p = 0; p < 2; ++p) {
          float e0 = EXP2(acc[2 * p]);
          float e1 = EXP2(acc[2 * p + 1]);
          unsigned u0 = __float_as_uint(e0) + 0x8000u;
          unsigned u1 = __float_as_uint(e1) + 0x8000u;
          pw[mi * 320 + nh * 8 + p] = pack_hi16(u1, u0);
        }
      }

    // reload P rows as A-frags (one ds_read_b128 per mi) and accumulate
#pragma unroll
    for (int mi = 0; mi < 2; ++mi) {
      bf16x8 ph = *(const bf16x8*)((unsigned short*)plds + (w * 32 + mi * 16 + c) * 40 + q * 8);
      oacc[mi] = __builtin_amdgcn_mfma_f32_16x16x32_bf16(ph, ah, oacc[mi], 0, 0, 0);
      oacc[mi] = __builtin_amdgcn_mfma_f32_16x16x32_bf16(ph, al, oacc[mi], 0, 0, 0);
    }
  }

  // apply exp(-0.5||z||^2) factor (pulled out of the n-loop) and accumulate
#pragma unroll
  for (int mi = 0; mi < 2; ++mi) {
    const float4* zp = (const float4*)(zs2 + (mc0 + mi) * 16) + q;
    float4 zv = *zp;
    float ez[4] = {EXP2(zv.x), EXP2(zv.y), EXP2(zv.z), EXP2(zv.w)};
#pragma unroll
    for (int r = 0; r < 4; ++r) {
      int m = blockIdx.x * 128 + w * 32 + mi * 16 + q * 4 + r;
      atomicAdd(&out[m * 16 + c], oacc[mi][r] * ez[r]);
    }
  }
}

extern "C" void kernel_launch(void* const* d_in, const int* in_sizes, int n_in,
                              void* d_out, int out_size, void* d_ws, size_t ws_size,
                              hipStream_t stream) {
  const float* z = (const float*)d_in[0];
  const float* dataset = (const float*)d_in[1];
  const float* alpha = (const float*)d_in[2];
  float* out = (float*)d_out;
  char* ws = (char*)d_ws;

  bf16x8* xph = (bf16x8*)ws;                     // 12,845,056 B
  bf16x8* xpl = xph + NC16 * 2 * 64;             // end 25,690,112
  bf16x8* aph = (bf16x8*)(ws + 25690112);        // 3,211,264 B
  bf16x8* apl = aph + NC32 * 64;                 // end 32,112,640
  bf16x8* zph = (bf16x8*)(ws + 32112640);        // 262,144 B
  bf16x8* zpl = zph + MC16 * 2 * 64;             // end 32,636,928
  float* xs2 = (float*)(ws + 32636928);          // NPAD floats
  float* zs2 = (float*)(ws + 33038336);          // B floats

  hipMemsetAsync(d_out, 0, (size_t)out_size * sizeof(float), stream);
  prep_pack_sq<<<dim3(NC16 / 4), dim3(256), 0, stream>>>(dataset, N_ACT, NC16, xph, xpl, xs2);
  prep_pack_sq<<<dim3(MC16 / 4), dim3(256), 0, stream>>>(z, B_ROWS, MC16, zph, zpl, zs2);
  prep_alpha<<<dim3(NC32 * 64 / 256), dim3(256), 0, stream>>>(alpha, aph, apl);
  rbf_main<<<dim3(MBLK, NSPLIT), dim3(256), 0, stream>>>(xph, xpl, aph, apl, zph, zpl, xs2, zs2, out);
}

// Round 3
// 153.549 us; speedup vs baseline: 1.6191x; 1.2588x over previous
//
#include <hip/hip_runtime.h>
#include <stdint.h>

#define N_ACT 100000
#define B_ROWS 2048
#define NPAD 100352          // 3136 * 32
#define NC16 (NPAD / 16)     // 6272
#define NC32 (NPAD / 32)     // 3136
#define MC16 (B_ROWS / 16)   // 128
#define NSPLIT 98
#define CPB (NC32 / NSPLIT)  // 32 n-chunks per block
#define MWAVE 64             // m-rows per wave (mi = 4)
#define MBLK (B_ROWS / 256)  // 8 m-blocks

#define SCALE 1.2011224087864498f   // sqrt(log2(e)); z'.x' = log2e * z.x
#define THRESH -40.5f               // skip tile if max log2(P) below this

typedef __attribute__((ext_vector_type(8))) short bf16x8;
typedef __attribute__((ext_vector_type(4))) float f32x4;

#if __has_builtin(__builtin_amdgcn_exp2f)
#define EXP2(x) __builtin_amdgcn_exp2f(x)
#else
#define EXP2(x) exp2f(x)
#endif

static __device__ __forceinline__ unsigned pack_hi16(unsigned u1, unsigned u0) {
#if __has_builtin(__builtin_amdgcn_perm)
  return __builtin_amdgcn_perm(u1, u0, 0x07060302u);
#else
  return (u1 & 0xffff0000u) | (u0 >> 16);
#endif
}

static __device__ __forceinline__ unsigned short f2bf(float f) {
  unsigned u = __float_as_uint(f);
  u += 0x7fffu + ((u >> 16) & 1u);
  return (unsigned short)(u >> 16);
}
static __device__ __forceinline__ float bf2f(unsigned short h) {
  return __uint_as_float(((unsigned)h) << 16);
}

// pack one 16-row chunk of a [rows x 64] fp32 matrix (scaled by SCALE) into
// hi/lo bf16 MFMA frags + sq[row] = -0.5*||scaled row||^2 (pad rows: -1e5)
static __device__ __forceinline__ void pack_wave(
    const float* __restrict__ src, int nvalid, int wid, int lane,
    bf16x8* __restrict__ dh, bf16x8* __restrict__ dl, float* __restrict__ sq) {
  int q = lane >> 4, c = lane & 15;
  int row = wid * 16 + c;
  float v[2][8];
  if (row < nvalid) {
    const float4* p0 = (const float4*)(src + row * 64 + q * 8);
    const float4* p1 = (const float4*)(src + row * 64 + 32 + q * 8);
    float4 a = p0[0], b = p0[1], e = p1[0], f = p1[1];
    v[0][0] = a.x * SCALE; v[0][1] = a.y * SCALE; v[0][2] = a.z * SCALE; v[0][3] = a.w * SCALE;
    v[0][4] = b.x * SCALE; v[0][5] = b.y * SCALE; v[0][6] = b.z * SCALE; v[0][7] = b.w * SCALE;
    v[1][0] = e.x * SCALE; v[1][1] = e.y * SCALE; v[1][2] = e.z * SCALE; v[1][3] = e.w * SCALE;
    v[1][4] = f.x * SCALE; v[1][5] = f.y * SCALE; v[1][6] = f.z * SCALE; v[1][7] = f.w * SCALE;
  } else {
#pragma unroll
    for (int kh = 0; kh < 2; ++kh)
#pragma unroll
      for (int j = 0; j < 8; ++j) v[kh][j] = 0.f;
  }
  float s = 0.f;
#pragma unroll
  for (int kh = 0; kh < 2; ++kh)
#pragma unroll
    for (int j = 0; j < 8; ++j) s += v[kh][j] * v[kh][j];
  s += __shfl_xor(s, 16, 64);
  s += __shfl_xor(s, 32, 64);
#pragma unroll
  for (int kh = 0; kh < 2; ++kh) {
    bf16x8 hv, lv;
#pragma unroll
    for (int j = 0; j < 8; ++j) {
      unsigned short h = f2bf(v[kh][j]);
      hv[j] = (short)h;
      lv[j] = (short)f2bf(v[kh][j] - bf2f(h));
    }
    dh[(wid * 2 + kh) * 64 + lane] = hv;
    dl[(wid * 2 + kh) * 64 + lane] = lv;
  }
  if (lane < 16) sq[wid * 16 + c] = (row < nvalid) ? (-0.5f * s) : -100000.f;
}

static __device__ __forceinline__ void alpha_wave(
    const float* __restrict__ alpha, int nc2, int lane,
    bf16x8* __restrict__ dh, bf16x8* __restrict__ dl) {
  int f = lane & 15, q = lane >> 4;
  bf16x8 hv, lv;
#pragma unroll
  for (int j = 0; j < 8; ++j) {
    int n = nc2 * 32 + q * 8 + j;
    float v = (n < N_ACT) ? alpha[n * 16 + f] : 0.f;
    unsigned short h = f2bf(v);
    hv[j] = (short)h;
    lv[j] = (short)f2bf(v - bf2f(h));
  }
  dh[nc2 * 64 + lane] = hv;
  dl[nc2 * 64 + lane] = lv;
}

// single fused prep dispatch: dataset chunks | z chunks | alpha chunks
__global__ void prep_all(const float* __restrict__ z, const float* __restrict__ dataset,
                         const float* __restrict__ alpha,
                         bf16x8* __restrict__ xph, bf16x8* __restrict__ xpl,
                         bf16x8* __restrict__ zph, bf16x8* __restrict__ zpl,
                         bf16x8* __restrict__ aph, bf16x8* __restrict__ apl,
                         float* __restrict__ xs2, float* __restrict__ zs2) {
  int gw = (blockIdx.x * 256 + threadIdx.x) >> 6;
  int lane = threadIdx.x & 63;
  if (gw < NC16) {
    pack_wave(dataset, N_ACT, gw, lane, xph, xpl, xs2);
  } else if (gw < NC16 + MC16) {
    pack_wave(z, B_ROWS, gw - NC16, lane, zph, zpl, zs2);
  } else {
    alpha_wave(alpha, gw - (NC16 + MC16), lane, aph, apl);
  }
}

// main: S_hh tile (64m x 32n per wave) -> wave-vote skip; rare path refines
// with cross lo terms, exp2, LDS round-trip, P@alpha MFMA. Partials out.
__global__ __launch_bounds__(256) void rbf_main(
    const bf16x8* __restrict__ xph, const bf16x8* __restrict__ xpl,
    const bf16x8* __restrict__ aph, const bf16x8* __restrict__ apl,
    const bf16x8* __restrict__ zph, const bf16x8* __restrict__ zpl,
    const float* __restrict__ xs2, const float* __restrict__ zs2,
    float* __restrict__ part) {
  __shared__ __align__(16) unsigned short plds[4][64][40];  // per-wave 64x32 bf16
  const int lane = threadIdx.x & 63;
  const int w = threadIdx.x >> 6;
  const int q = lane >> 4, c = lane & 15;
  const int mb = blockIdx.x * 256 + w * 64;  // wave m-base
  const int mc0 = mb >> 4;                   // m-chunk16 base

  // persistent z hi fragments (B operand)
  bf16x8 zfh[4][2];
#pragma unroll
  for (int mi = 0; mi < 4; ++mi)
#pragma unroll
    for (int kh = 0; kh < 2; ++kh)
      zfh[mi][kh] = zph[((mc0 + mi) * 2 + kh) * 64 + lane];

  // per-lane z row constants: this lane's cols are m = mi*16 + c
  float zq[4], thr[4];
#pragma unroll
  for (int mi = 0; mi < 4; ++mi) {
    zq[mi] = zs2[mb + mi * 16 + c];
    thr[mi] = THRESH - zq[mi];
  }

  f32x4 oacc[4];
#pragma unroll
  for (int mi = 0; mi < 4; ++mi) oacc[mi] = (f32x4){0.f, 0.f, 0.f, 0.f};

  unsigned* pwbase = (unsigned*)plds + (w * 64 + c) * 20 + q * 2;

  const int nc2_0 = blockIdx.y * CPB;
  for (int it = 0; it < CPB; ++it) {
    const int nc2 = nc2_0 + it;
    // x hi fragments (A operand) + row norms
    bf16x8 xfh[2][2];
#pragma unroll
    for (int nh = 0; nh < 2; ++nh)
#pragma unroll
      for (int kh = 0; kh < 2; ++kh)
        xfh[nh][kh] = xph[((nc2 * 2 + nh) * 2 + kh) * 64 + lane];
    f32x4 xq[2];
#pragma unroll
    for (int nh = 0; nh < 2; ++nh) {
      float4 t = *((const float4*)(xs2 + nc2 * 32 + nh * 16) + q);
      xq[nh] = (f32x4){t.x, t.y, t.z, t.w};
    }

    // S_hh = x_hi.z_hi^T - 0.5||x||^2   (z-norm folded into threshold)
    f32x4 acc[4][2];
#pragma unroll
    for (int mi = 0; mi < 4; ++mi)
#pragma unroll
      for (int nh = 0; nh < 2; ++nh) {
        f32x4 a = xq[nh];
        a = __builtin_amdgcn_mfma_f32_16x16x32_bf16(xfh[nh][0], zfh[mi][0], a, 0, 0, 0);
        a = __builtin_amdgcn_mfma_f32_16x16x32_bf16(xfh[nh][1], zfh[mi][1], a, 0, 0, 0);
        acc[mi][nh] = a;
      }

    // wave-uniform skip vote: any log2(P) estimate above threshold?
    float d = -1.f;
#pragma unroll
    for (int mi = 0; mi < 4; ++mi) {
      float mx = acc[mi][0][0];
#pragma unroll
      for (int r = 1; r < 4; ++r) mx = fmaxf(mx, acc[mi][0][r]);
#pragma unroll
      for (int r = 0; r < 4; ++r) mx = fmaxf(mx, acc[mi][1][r]);
      d = fmaxf(d, mx - thr[mi]);
    }
    if (!__any(d > 0.f)) continue;  // ~95% of tiles

    // ---- rare path: refine S with hi*lo + lo*hi, then P @ alpha ----
    bf16x8 xfl[2][2];
#pragma unroll
    for (int nh = 0; nh < 2; ++nh)
#pragma unroll
      for (int kh = 0; kh < 2; ++kh)
        xfl[nh][kh] = xpl[((nc2 * 2 + nh) * 2 + kh) * 64 + lane];

#pragma unroll
    for (int mi = 0; mi < 4; ++mi) {
      bf16x8 zl0 = zpl[((mc0 + mi) * 2 + 0) * 64 + lane];
      bf16x8 zl1 = zpl[((mc0 + mi) * 2 + 1) * 64 + lane];
#pragma unroll
      for (int nh = 0; nh < 2; ++nh) {
        f32x4 a = acc[mi][nh];
        a = __builtin_amdgcn_mfma_f32_16x16x32_bf16(xfh[nh][0], zl0, a, 0, 0, 0);
        a = __builtin_amdgcn_mfma_f32_16x16x32_bf16(xfl[nh][0], zfh[mi][0], a, 0, 0, 0);
        a = __builtin_amdgcn_mfma_f32_16x16x32_bf16(xfh[nh][1], zl1, a, 0, 0, 0);
        a = __builtin_amdgcn_mfma_f32_16x16x32_bf16(xfl[nh][1], zfh[mi][1], a, 0, 0, 0);
        // P = 2^(S - 0.5||x||^2 - 0.5||z||^2), bf16 round-half-up, pack pairs
#pragma unroll
        for (int p = 0; p < 2; ++p) {
          float e0 = EXP2(a[2 * p] + zq[mi]);
          float e1 = EXP2(a[2 * p + 1] + zq[mi]);
          unsigned u0 = __float_as_uint(e0) + 0x8000u;
          unsigned u1 = __float_as_uint(e1) + 0x8000u;
          pwbase[(mi * 16) * 20 + nh * 8 + p] = pack_hi16(u1, u0);
        }
      }
    }
    bf16x8 ah = aph[nc2 * 64 + lane];
    bf16x8 al = apl[nc2 * 64 + lane];
#pragma unroll
    for (int mi = 0; mi < 4; ++mi) {
      bf16x8 ph = *(const bf16x8*)((unsigned short*)plds + (w * 64 + mi * 16 + c) * 40 + q * 8);
      oacc[mi] = __builtin_amdgcn_mfma_f32_16x16x32_bf16(ph, ah, oacc[mi], 0, 0, 0);
      oacc[mi] = __builtin_amdgcn_mfma_f32_16x16x32_bf16(ph, al, oacc[mi], 0, 0, 0);
    }
  }

  // write partials (every element of this wave's slice, even if zero)
  float* pp = part + (size_t)blockIdx.y * (B_ROWS * 16);
#pragma unroll
  for (int mi = 0; mi < 4; ++mi)
#pragma unroll
    for (int r = 0; r < 4; ++r)
      pp[(mb + mi * 16 + q * 4 + r) * 16 + c] = oacc[mi][r];
}

__global__ void reduce_parts(const float* __restrict__ part, float* __restrict__ out) {
  int t = blockIdx.x * 256 + threadIdx.x;  // 32768 threads
  float s = 0.f;
  for (int y = 0; y < NSPLIT; ++y) s += part[y * (B_ROWS * 16) + t];
  out[t] = s;
}

extern "C" void kernel_launch(void* const* d_in, const int* in_sizes, int n_in,
                              void* d_out, int out_size, void* d_ws, size_t ws_size,
                              hipStream_t stream) {
  const float* z = (const float*)d_in[0];
  const float* dataset = (const float*)d_in[1];
  const float* alpha = (const float*)d_in[2];
  float* out = (float*)d_out;
  char* ws = (char*)d_ws;

  bf16x8* xph = (bf16x8*)ws;                       // 12,845,056
  bf16x8* xpl = xph + NC16 * 2 * 64;               // -> 25,690,112
  bf16x8* aph = (bf16x8*)(ws + 25690112);          // 3,211,264
  bf16x8* apl = aph + NC32 * 64;                   // -> 32,112,640
  bf16x8* zph = (bf16x8*)(ws + 32112640);          // 262,144
  bf16x8* zpl = zph + MC16 * 2 * 64;               // -> 32,636,928
  float* xs2 = (float*)(ws + 32636928);            // NPAD floats -> 33,038,336
  float* zs2 = (float*)(ws + 33038336);            // 2048 floats -> 33,046,528
  float* part = (float*)(ws + 33046528);           // 98*2048*16 f32 = 12,845,056

  int prep_waves = NC16 + MC16 + NC32;             // 9536
  prep_all<<<dim3((prep_waves + 3) / 4), dim3(256), 0, stream>>>(
      z, dataset, alpha, xph, xpl, zph, zpl, aph, apl, xs2, zs2);
  rbf_main<<<dim3(MBLK, NSPLIT), dim3(256), 0, stream>>>(
      xph, xpl, aph, apl, zph, zpl, xs2, zs2, part);
  reduce_parts<<<dim3(B_ROWS * 16 / 256), dim3(256), 0, stream>>>(part, out);
}

// Round 5
// 138.455 us; speedup vs baseline: 1.7957x; 1.1090x over previous
//
#include <hip/hip_runtime.h>
#include <stdint.h>

#define N_ACT 100000
#define B_ROWS 2048
#define NPAD 100352          // 3136 * 32
#define NC16 (NPAD / 16)     // 6272
#define NC32 (NPAD / 32)     // 3136
#define MC16 (B_ROWS / 16)   // 128
#define NSPLIT 196
#define CPB (NC32 / NSPLIT)  // 16 n-chunks per block
#define MBLK (B_ROWS / 256)  // 8 m-blocks
#define GRID (MBLK * NSPLIT) // 1568

#define SCALE 1.2011224087864498f   // sqrt(log2(e)); z'.x' = log2e * z.x
#define THRESH -40.5f               // skip tile if max log2(P) below this

typedef __attribute__((ext_vector_type(8))) short bf16x8;
typedef __attribute__((ext_vector_type(4))) float f32x4;

#if __has_builtin(__builtin_amdgcn_exp2f)
#define EXP2(x) __builtin_amdgcn_exp2f(x)
#else
#define EXP2(x) exp2f(x)
#endif

static __device__ __forceinline__ unsigned pack_hi16(unsigned u1, unsigned u0) {
#if __has_builtin(__builtin_amdgcn_perm)
  return __builtin_amdgcn_perm(u1, u0, 0x07060302u);
#else
  return (u1 & 0xffff0000u) | (u0 >> 16);
#endif
}

static __device__ __forceinline__ unsigned short f2bf(float f) {
  unsigned u = __float_as_uint(f);
  u += 0x7fffu + ((u >> 16) & 1u);
  return (unsigned short)(u >> 16);
}
static __device__ __forceinline__ float bf2f(unsigned short h) {
  return __uint_as_float(((unsigned)h) << 16);
}

// pack one 16-row chunk of a [rows x 64] fp32 matrix (scaled by SCALE) into
// hi/lo bf16 MFMA frags + sq[row] = -0.5*||scaled row||^2 (pad rows: -1e5)
static __device__ __forceinline__ void pack_wave(
    const float* __restrict__ src, int nvalid, int wid, int lane,
    bf16x8* __restrict__ dh, bf16x8* __restrict__ dl, float* __restrict__ sq) {
  int q = lane >> 4, c = lane & 15;
  int row = wid * 16 + c;
  float v[2][8];
  if (row < nvalid) {
    const float4* p0 = (const float4*)(src + row * 64 + q * 8);
    const float4* p1 = (const float4*)(src + row * 64 + 32 + q * 8);
    float4 a = p0[0], b = p0[1], e = p1[0], f = p1[1];
    v[0][0] = a.x * SCALE; v[0][1] = a.y * SCALE; v[0][2] = a.z * SCALE; v[0][3] = a.w * SCALE;
    v[0][4] = b.x * SCALE; v[0][5] = b.y * SCALE; v[0][6] = b.z * SCALE; v[0][7] = b.w * SCALE;
    v[1][0] = e.x * SCALE; v[1][1] = e.y * SCALE; v[1][2] = e.z * SCALE; v[1][3] = e.w * SCALE;
    v[1][4] = f.x * SCALE; v[1][5] = f.y * SCALE; v[1][6] = f.z * SCALE; v[1][7] = f.w * SCALE;
  } else {
#pragma unroll
    for (int kh = 0; kh < 2; ++kh)
#pragma unroll
      for (int j = 0; j < 8; ++j) v[kh][j] = 0.f;
  }
  float s = 0.f;
#pragma unroll
  for (int kh = 0; kh < 2; ++kh)
#pragma unroll
    for (int j = 0; j < 8; ++j) s += v[kh][j] * v[kh][j];
  s += __shfl_xor(s, 16, 64);
  s += __shfl_xor(s, 32, 64);
#pragma unroll
  for (int kh = 0; kh < 2; ++kh) {
    bf16x8 hv, lv;
#pragma unroll
    for (int j = 0; j < 8; ++j) {
      unsigned short h = f2bf(v[kh][j]);
      hv[j] = (short)h;
      lv[j] = (short)f2bf(v[kh][j] - bf2f(h));
    }
    dh[(wid * 2 + kh) * 64 + lane] = hv;
    dl[(wid * 2 + kh) * 64 + lane] = lv;
  }
  if (lane < 16) sq[wid * 16 + c] = (row < nvalid) ? (-0.5f * s) : -100000.f;
}

static __device__ __forceinline__ void alpha_wave(
    const float* __restrict__ alpha, int nc2, int lane,
    bf16x8* __restrict__ dh, bf16x8* __restrict__ dl) {
  int f = lane & 15, q = lane >> 4;
  bf16x8 hv, lv;
#pragma unroll
  for (int j = 0; j < 8; ++j) {
    int n = nc2 * 32 + q * 8 + j;
    float v = (n < N_ACT) ? alpha[n * 16 + f] : 0.f;
    unsigned short h = f2bf(v);
    hv[j] = (short)h;
    lv[j] = (short)f2bf(v - bf2f(h));
  }
  dh[nc2 * 64 + lane] = hv;
  dl[nc2 * 64 + lane] = lv;
}

__global__ void prep_all(const float* __restrict__ z, const float* __restrict__ dataset,
                         const float* __restrict__ alpha,
                         bf16x8* __restrict__ xph, bf16x8* __restrict__ xpl,
                         bf16x8* __restrict__ zph, bf16x8* __restrict__ zpl,
                         bf16x8* __restrict__ aph, bf16x8* __restrict__ apl,
                         float* __restrict__ xs2, float* __restrict__ zs2) {
  int gw = (blockIdx.x * 256 + threadIdx.x) >> 6;
  int lane = threadIdx.x & 63;
  if (gw < NC16) {
    pack_wave(dataset, N_ACT, gw, lane, xph, xpl, xs2);
  } else if (gw < NC16 + MC16) {
    pack_wave(z, B_ROWS, gw - NC16, lane, zph, zpl, zs2);
  } else {
    alpha_wave(alpha, gw - (NC16 + MC16), lane, aph, apl);
  }
}

// main: S_hh tile (64m x 32n per wave) with distance-1 register prefetch of
// the x stream; wave-vote skip; rare path refines + P@alpha; atomic output.
// NOTE: exp(-0.5||z||^2) is folded into the rare-path EXP2 (zq) — do NOT
// apply it again in the epilogue (round-4 bug: double application).
__global__ __launch_bounds__(256) void rbf_main(
    const bf16x8* __restrict__ xph, const bf16x8* __restrict__ xpl,
    const bf16x8* __restrict__ aph, const bf16x8* __restrict__ apl,
    const bf16x8* __restrict__ zph, const bf16x8* __restrict__ zpl,
    const float* __restrict__ xs2, const float* __restrict__ zs2,
    float* __restrict__ out) {
  __shared__ __align__(16) unsigned short plds[4][64][40];  // per-wave 64x32 bf16
  const int lane = threadIdx.x & 63;
  const int w = threadIdx.x >> 6;
  const int q = lane >> 4, c = lane & 15;
  const int bid = blockIdx.x;
  const int yb = bid % NSPLIT;       // same-y blocks differ by 196 -> 2 XCDs
  const int mbi = bid / NSPLIT;
  const int mb = mbi * 256 + w * 64; // wave m-base
  const int mc0 = mb >> 4;

  // persistent z hi fragments (B operand)
  bf16x8 zfh[4][2];
#pragma unroll
  for (int mi = 0; mi < 4; ++mi)
#pragma unroll
    for (int kh = 0; kh < 2; ++kh)
      zfh[mi][kh] = zph[((mc0 + mi) * 2 + kh) * 64 + lane];

  float zq[4], thr[4];
#pragma unroll
  for (int mi = 0; mi < 4; ++mi) {
    zq[mi] = zs2[mb + mi * 16 + c];
    thr[mi] = THRESH - zq[mi];
  }

  f32x4 oacc[4];
#pragma unroll
  for (int mi = 0; mi < 4; ++mi) oacc[mi] = (f32x4){0.f, 0.f, 0.f, 0.f};
  int hit = 0;

  unsigned* pwbase = (unsigned*)plds + (w * 64 + c) * 20 + q * 2;
  const int nc2_0 = yb * CPB;

  // prologue: prefetch iteration 0
  bf16x8 xfn[2][2];
  f32x4 xqn[2];
#pragma unroll
  for (int nh = 0; nh < 2; ++nh) {
#pragma unroll
    for (int kh = 0; kh < 2; ++kh)
      xfn[nh][kh] = xph[((nc2_0 * 2 + nh) * 2 + kh) * 64 + lane];
    float4 t = *((const float4*)(xs2 + nc2_0 * 32 + nh * 16) + q);
    xqn[nh] = (f32x4){t.x, t.y, t.z, t.w};
  }

#pragma unroll 2
  for (int it = 0; it < CPB; ++it) {
    const int nc2 = nc2_0 + it;
    // rotate prefetch regs into current
    bf16x8 xfh[2][2];
    f32x4 xq[2];
#pragma unroll
    for (int nh = 0; nh < 2; ++nh) {
      xfh[nh][0] = xfn[nh][0];
      xfh[nh][1] = xfn[nh][1];
      xq[nh] = xqn[nh];
    }
    // issue next-iter loads now (unguarded: over-read stays inside d_ws)
    {
      const int nn = nc2 + 1;
#pragma unroll
      for (int nh = 0; nh < 2; ++nh) {
#pragma unroll
        for (int kh = 0; kh < 2; ++kh)
          xfn[nh][kh] = xph[((nn * 2 + nh) * 2 + kh) * 64 + lane];
        float4 t = *((const float4*)(xs2 + nn * 32 + nh * 16) + q);
        xqn[nh] = (f32x4){t.x, t.y, t.z, t.w};
      }
    }

    // S_hh = x_hi.z_hi^T - 0.5||x||^2   (z-norm folded into threshold)
    f32x4 acc[4][2];
#pragma unroll
    for (int mi = 0; mi < 4; ++mi)
#pragma unroll
      for (int nh = 0; nh < 2; ++nh) {
        f32x4 a = xq[nh];
        a = __builtin_amdgcn_mfma_f32_16x16x32_bf16(xfh[nh][0], zfh[mi][0], a, 0, 0, 0);
        a = __builtin_amdgcn_mfma_f32_16x16x32_bf16(xfh[nh][1], zfh[mi][1], a, 0, 0, 0);
        acc[mi][nh] = a;
      }

    // wave-uniform skip vote
    float d = -1.f;
#pragma unroll
    for (int mi = 0; mi < 4; ++mi) {
      float mx = fmaxf(fmaxf(acc[mi][0][0], acc[mi][0][1]),
                       fmaxf(acc[mi][0][2], acc[mi][0][3]));
      mx = fmaxf(mx, fmaxf(fmaxf(acc[mi][1][0], acc[mi][1][1]),
                           fmaxf(acc[mi][1][2], acc[mi][1][3])));
      d = fmaxf(d, mx - thr[mi]);
    }
    if (!__any(d > 0.f)) continue;  // ~95% of tiles

    // ---- rare path ----
    hit = 1;
    bf16x8 xfl[2][2];
#pragma unroll
    for (int nh = 0; nh < 2; ++nh)
#pragma unroll
      for (int kh = 0; kh < 2; ++kh)
        xfl[nh][kh] = xpl[((nc2 * 2 + nh) * 2 + kh) * 64 + lane];

#pragma unroll
    for (int mi = 0; mi < 4; ++mi) {
      bf16x8 zl0 = zpl[((mc0 + mi) * 2 + 0) * 64 + lane];
      bf16x8 zl1 = zpl[((mc0 + mi) * 2 + 1) * 64 + lane];
#pragma unroll
      for (int nh = 0; nh < 2; ++nh) {
        f32x4 a = acc[mi][nh];
        a = __builtin_amdgcn_mfma_f32_16x16x32_bf16(xfh[nh][0], zl0, a, 0, 0, 0);
        a = __builtin_amdgcn_mfma_f32_16x16x32_bf16(xfl[nh][0], zfh[mi][0], a, 0, 0, 0);
        a = __builtin_amdgcn_mfma_f32_16x16x32_bf16(xfh[nh][1], zl1, a, 0, 0, 0);
        a = __builtin_amdgcn_mfma_f32_16x16x32_bf16(xfl[nh][1], zfh[mi][1], a, 0, 0, 0);
        // P = 2^(S' + zq) — z-factor applied HERE, once.
#pragma unroll
        for (int p = 0; p < 2; ++p) {
          float e0 = EXP2(a[2 * p] + zq[mi]);
          float e1 = EXP2(a[2 * p + 1] + zq[mi]);
          unsigned u0 = __float_as_uint(e0) + 0x8000u;
          unsigned u1 = __float_as_uint(e1) + 0x8000u;
          pwbase[(mi * 16) * 20 + nh * 8 + p] = pack_hi16(u1, u0);
        }
      }
    }
    bf16x8 ah = aph[nc2 * 64 + lane];
    bf16x8 al = apl[nc2 * 64 + lane];
#pragma unroll
    for (int mi = 0; mi < 4; ++mi) {
      bf16x8 ph = *(const bf16x8*)((unsigned short*)plds + (w * 64 + mi * 16 + c) * 40 + q * 8);
      oacc[mi] = __builtin_amdgcn_mfma_f32_16x16x32_bf16(ph, ah, oacc[mi], 0, 0, 0);
      oacc[mi] = __builtin_amdgcn_mfma_f32_16x16x32_bf16(ph, al, oacc[mi], 0, 0, 0);
    }
  }

  if (hit) {  // wave-uniform; waves with no rare tile contribute nothing
#pragma unroll
    for (int mi = 0; mi < 4; ++mi)
#pragma unroll
      for (int r = 0; r < 4; ++r) {
        int m = mb + mi * 16 + q * 4 + r;
        atomicAdd(&out[m * 16 + c], oacc[mi][r]);
      }
  }
}

extern "C" void kernel_launch(void* const* d_in, const int* in_sizes, int n_in,
                              void* d_out, int out_size, void* d_ws, size_t ws_size,
                              hipStream_t stream) {
  const float* z = (const float*)d_in[0];
  const float* dataset = (const float*)d_in[1];
  const float* alpha = (const float*)d_in[2];
  float* out = (float*)d_out;
  char* ws = (char*)d_ws;

  bf16x8* xph = (bf16x8*)ws;                       // 12,845,056
  bf16x8* xpl = xph + NC16 * 2 * 64;               // -> 25,690,112
  bf16x8* aph = (bf16x8*)(ws + 25690112);          // 3,211,264
  bf16x8* apl = aph + NC32 * 64;                   // -> 32,112,640
  bf16x8* zph = (bf16x8*)(ws + 32112640);          // 262,144
  bf16x8* zpl = zph + MC16 * 2 * 64;               // -> 32,636,928
  float* xs2 = (float*)(ws + 32636928);            // NPAD floats -> 33,038,336
  float* zs2 = (float*)(ws + 33038336);            // 2048 floats -> 33,046,528

  hipMemsetAsync(d_out, 0, (size_t)out_size * sizeof(float), stream);
  int prep_waves = NC16 + MC16 + NC32;             // 9536
  prep_all<<<dim3((prep_waves + 3) / 4), dim3(256), 0, stream>>>(
      z, dataset, alpha, xph, xpl, zph, zpl, aph, apl, xs2, zs2);
  rbf_main<<<dim3(GRID), dim3(256), 0, stream>>>(
      xph, xpl, aph, apl, zph, zpl, xs2, zs2, out);
}

// Round 6
// 129.624 us; speedup vs baseline: 1.9180x; 1.0681x over previous
//
#include <hip/hip_runtime.h>
#include <stdint.h>

#define N_ACT 100000
#define B_ROWS 2048
#define NPAD 100352          // 3136 * 32
#define NC16 (NPAD / 16)     // 6272
#define NC32 (NPAD / 32)     // 3136
#define MC16 (B_ROWS / 16)   // 128
#define NSPLIT 224           // divisible by 8 -> same-slice blocks share bid%8 (one XCD)
#define CPB (NC32 / NSPLIT)  // 14 n-chunks per block
#define MBLK (B_ROWS / 256)  // 8 m-blocks
#define GRID (MBLK * NSPLIT) // 1792

#define SCALE 1.2011224087864498f   // sqrt(log2(e)); z'.x' = log2e * z.x
#define THRESH -40.5f               // skip tile if max log2(P) below this

typedef __attribute__((ext_vector_type(8))) short bf16x8;
typedef __attribute__((ext_vector_type(4))) float f32x4;

#if __has_builtin(__builtin_amdgcn_exp2f)
#define EXP2(x) __builtin_amdgcn_exp2f(x)
#else
#define EXP2(x) exp2f(x)
#endif

static __device__ __forceinline__ unsigned pack_hi16(unsigned u1, unsigned u0) {
#if __has_builtin(__builtin_amdgcn_perm)
  return __builtin_amdgcn_perm(u1, u0, 0x07060302u);
#else
  return (u1 & 0xffff0000u) | (u0 >> 16);
#endif
}

static __device__ __forceinline__ unsigned short f2bf(float f) {
  unsigned u = __float_as_uint(f);
  u += 0x7fffu + ((u >> 16) & 1u);
  return (unsigned short)(u >> 16);
}
static __device__ __forceinline__ float bf2f(unsigned short h) {
  return __uint_as_float(((unsigned)h) << 16);
}

static __device__ __forceinline__ void pack_wave(
    const float* __restrict__ src, int nvalid, int wid, int lane,
    bf16x8* __restrict__ dh, bf16x8* __restrict__ dl, float* __restrict__ sq) {
  int q = lane >> 4, c = lane & 15;
  int row = wid * 16 + c;
  float v[2][8];
  if (row < nvalid) {
    const float4* p0 = (const float4*)(src + row * 64 + q * 8);
    const float4* p1 = (const float4*)(src + row * 64 + 32 + q * 8);
    float4 a = p0[0], b = p0[1], e = p1[0], f = p1[1];
    v[0][0] = a.x * SCALE; v[0][1] = a.y * SCALE; v[0][2] = a.z * SCALE; v[0][3] = a.w * SCALE;
    v[0][4] = b.x * SCALE; v[0][5] = b.y * SCALE; v[0][6] = b.z * SCALE; v[0][7] = b.w * SCALE;
    v[1][0] = e.x * SCALE; v[1][1] = e.y * SCALE; v[1][2] = e.z * SCALE; v[1][3] = e.w * SCALE;
    v[1][4] = f.x * SCALE; v[1][5] = f.y * SCALE; v[1][6] = f.z * SCALE; v[1][7] = f.w * SCALE;
  } else {
#pragma unroll
    for (int kh = 0; kh < 2; ++kh)
#pragma unroll
      for (int j = 0; j < 8; ++j) v[kh][j] = 0.f;
  }
  float s = 0.f;
#pragma unroll
  for (int kh = 0; kh < 2; ++kh)
#pragma unroll
    for (int j = 0; j < 8; ++j) s += v[kh][j] * v[kh][j];
  s += __shfl_xor(s, 16, 64);
  s += __shfl_xor(s, 32, 64);
#pragma unroll
  for (int kh = 0; kh < 2; ++kh) {
    bf16x8 hv, lv;
#pragma unroll
    for (int j = 0; j < 8; ++j) {
      unsigned short h = f2bf(v[kh][j]);
      hv[j] = (short)h;
      lv[j] = (short)f2bf(v[kh][j] - bf2f(h));
    }
    dh[(wid * 2 + kh) * 64 + lane] = hv;
    dl[(wid * 2 + kh) * 64 + lane] = lv;
  }
  if (lane < 16) sq[wid * 16 + c] = (row < nvalid) ? (-0.5f * s) : -100000.f;
}

static __device__ __forceinline__ void alpha_wave(
    const float* __restrict__ alpha, int nc2, int lane,
    bf16x8* __restrict__ dh, bf16x8* __restrict__ dl) {
  int f = lane & 15, q = lane >> 4;
  bf16x8 hv, lv;
#pragma unroll
  for (int j = 0; j < 8; ++j) {
    int n = nc2 * 32 + q * 8 + j;
    float v = (n < N_ACT) ? alpha[n * 16 + f] : 0.f;
    unsigned short h = f2bf(v);
    hv[j] = (short)h;
    lv[j] = (short)f2bf(v - bf2f(h));
  }
  dh[nc2 * 64 + lane] = hv;
  dl[nc2 * 64 + lane] = lv;
}

__global__ void prep_all(const float* __restrict__ z, const float* __restrict__ dataset,
                         const float* __restrict__ alpha,
                         bf16x8* __restrict__ xph, bf16x8* __restrict__ xpl,
                         bf16x8* __restrict__ zph, bf16x8* __restrict__ zpl,
                         bf16x8* __restrict__ aph, bf16x8* __restrict__ apl,
                         float* __restrict__ xs2, float* __restrict__ zs2) {
  int gw = (blockIdx.x * 256 + threadIdx.x) >> 6;
  int lane = threadIdx.x & 63;
  if (gw < NC16) {
    pack_wave(dataset, N_ACT, gw, lane, xph, xpl, xs2);
  } else if (gw < NC16 + MC16) {
    pack_wave(z, B_ROWS, gw - NC16, lane, zph, zpl, zs2);
  } else {
    alpha_wave(alpha, gw - (NC16 + MC16), lane, aph, apl);
  }
}

// One pipeline step for n-chunk NC2 using ping-pong slot (XF,XQ).
// Order: MFMAs read slot -> refill slot for NC2+2 (WAR only, no wait) -> vote.
// Rare path reloads x hi/lo from global (L1/L2-hot) since slot is refilled.
// exp(-0.5||z||^2) folded into EXP2 via zq — applied exactly once.
#define RBF_STEP(NC2, XF, XQ)                                                   \
  do {                                                                          \
    const int nc2_ = (NC2);                                                     \
    f32x4 acc[4][2];                                                            \
    _Pragma("unroll") for (int mi = 0; mi < 4; ++mi) {                          \
      _Pragma("unroll") for (int nh = 0; nh < 2; ++nh) {                        \
        f32x4 a = __builtin_amdgcn_mfma_f32_16x16x32_bf16(                      \
            XF[nh][0], zfh[mi][0], XQ[nh], 0, 0, 0);                            \
        acc[mi][nh] = __builtin_amdgcn_mfma_f32_16x16x32_bf16(                  \
            XF[nh][1], zfh[mi][1], a, 0, 0, 0);                                 \
      }                                                                         \
    }                                                                           \
    {                                                                           \
      const int nn = nc2_ + 2; /* unguarded over-read stays inside d_ws */      \
      _Pragma("unroll") for (int nh = 0; nh < 2; ++nh) {                        \
        _Pragma("unroll") for (int kh = 0; kh < 2; ++kh)                        \
          XF[nh][kh] = xphb[(nn * 4 + nh * 2 + kh) * 64];                       \
        float4 t = *(const float4*)(xs2 + nn * 32 + nh * 16 + q * 4);           \
        XQ[nh] = (f32x4){t.x, t.y, t.z, t.w};                                   \
      }                                                                         \
    }                                                                           \
    float d = -1e30f;                                                           \
    _Pragma("unroll") for (int mi = 0; mi < 4; ++mi) {                          \
      float mx = fmaxf(fmaxf(acc[mi][0][0], acc[mi][0][1]),                     \
                       fmaxf(acc[mi][0][2], acc[mi][0][3]));                    \
      mx = fmaxf(mx, fmaxf(fmaxf(acc[mi][1][0], acc[mi][1][1]),                 \
                           fmaxf(acc[mi][1][2], acc[mi][1][3])));               \
      d = fmaxf(d, mx + zq[mi]);                                                \
    }                                                                           \
    if (__any(d > THRESH)) {                                                    \
      hit = 1;                                                                  \
      bf16x8 rh[2][2], rl[2][2];                                                \
      _Pragma("unroll") for (int nh = 0; nh < 2; ++nh)                          \
        _Pragma("unroll") for (int kh = 0; kh < 2; ++kh) {                      \
          rh[nh][kh] = xphb[(nc2_ * 4 + nh * 2 + kh) * 64];                     \
          rl[nh][kh] = xplb[(nc2_ * 4 + nh * 2 + kh) * 64];                     \
        }                                                                       \
      bf16x8 ah = aphb[nc2_ * 64];                                              \
      bf16x8 al = aplb[nc2_ * 64];                                              \
      _Pragma("unroll") for (int mi = 0; mi < 4; ++mi) {                        \
        bf16x8 zl0 = zplb[mi * 128];                                            \
        bf16x8 zl1 = zplb[mi * 128 + 64];                                       \
        _Pragma("unroll") for (int nh = 0; nh < 2; ++nh) {                      \
          f32x4 a = acc[mi][nh];                                                \
          a = __builtin_amdgcn_mfma_f32_16x16x32_bf16(rh[nh][0], zl0, a, 0, 0, 0);       \
          a = __builtin_amdgcn_mfma_f32_16x16x32_bf16(rl[nh][0], zfh[mi][0], a, 0, 0, 0);\
          a = __builtin_amdgcn_mfma_f32_16x16x32_bf16(rh[nh][1], zl1, a, 0, 0, 0);       \
          a = __builtin_amdgcn_mfma_f32_16x16x32_bf16(rl[nh][1], zfh[mi][1], a, 0, 0, 0);\
          _Pragma("unroll") for (int p = 0; p < 2; ++p) {                       \
            float e0 = EXP2(a[2 * p] + zq[mi]);                                 \
            float e1 = EXP2(a[2 * p + 1] + zq[mi]);                             \
            unsigned u0 = __float_as_uint(e0) + 0x8000u;                        \
            unsigned u1 = __float_as_uint(e1) + 0x8000u;                        \
            pwbase[(mi * 16) * 20 + nh * 8 + p] = pack_hi16(u1, u0);            \
          }                                                                     \
        }                                                                       \
      }                                                                         \
      _Pragma("unroll") for (int mi = 0; mi < 4; ++mi) {                        \
        bf16x8 ph = *(const bf16x8*)(prdb + mi * 640);                          \
        oacc[mi] = __builtin_amdgcn_mfma_f32_16x16x32_bf16(ph, ah, oacc[mi], 0, 0, 0);   \
        oacc[mi] = __builtin_amdgcn_mfma_f32_16x16x32_bf16(ph, al, oacc[mi], 0, 0, 0);   \
      }                                                                         \
    }                                                                           \
  } while (0)

__global__ __launch_bounds__(256) void rbf_main(
    const bf16x8* __restrict__ xph, const bf16x8* __restrict__ xpl,
    const bf16x8* __restrict__ aph, const bf16x8* __restrict__ apl,
    const bf16x8* __restrict__ zph, const bf16x8* __restrict__ zpl,
    const float* __restrict__ xs2, const float* __restrict__ zs2,
    float* __restrict__ out) {
  __shared__ __align__(16) unsigned short plds[4][64][40];  // per-wave 64x32 bf16
  const int lane = threadIdx.x & 63;
  const int w = threadIdx.x >> 6;
  const int q = lane >> 4, c = lane & 15;
  const int bid = blockIdx.x;
  const int yb = bid % NSPLIT;   // 224%8==0 -> all 8 same-yb blocks on one XCD
  const int mbi = bid / NSPLIT;
  const int mb = mbi * 256 + w * 64;
  const int mc0 = mb >> 4;

  const bf16x8* xphb = xph + lane;
  const bf16x8* xplb = xpl + lane;
  const bf16x8* aphb = aph + lane;
  const bf16x8* aplb = apl + lane;
  const bf16x8* zplb = zpl + mc0 * 2 * 64 + lane;

  bf16x8 zfh[4][2];
#pragma unroll
  for (int mi = 0; mi < 4; ++mi)
#pragma unroll
    for (int kh = 0; kh < 2; ++kh)
      zfh[mi][kh] = zph[((mc0 + mi) * 2 + kh) * 64 + lane];

  float zq[4];
#pragma unroll
  for (int mi = 0; mi < 4; ++mi) zq[mi] = zs2[mb + mi * 16 + c];

  f32x4 oacc[4];
#pragma unroll
  for (int mi = 0; mi < 4; ++mi) oacc[mi] = (f32x4){0.f, 0.f, 0.f, 0.f};
  int hit = 0;

  unsigned* pwbase = (unsigned*)plds + (w * 64 + c) * 20 + q * 2;
  const unsigned short* prdb = (unsigned short*)plds + (w * 64 + c) * 40 + q * 8;
  const int nc2_0 = yb * CPB;

  // prologue: fill both pipeline slots (it=0 and it=1)
  bf16x8 xb0[2][2], xb1[2][2];
  f32x4 xq0[2], xq1[2];
#pragma unroll
  for (int nh = 0; nh < 2; ++nh) {
#pragma unroll
    for (int kh = 0; kh < 2; ++kh) {
      xb0[nh][kh] = xphb[(nc2_0 * 4 + nh * 2 + kh) * 64];
      xb1[nh][kh] = xphb[((nc2_0 + 1) * 4 + nh * 2 + kh) * 64];
    }
    float4 t0 = *(const float4*)(xs2 + nc2_0 * 32 + nh * 16 + q * 4);
    float4 t1 = *(const float4*)(xs2 + (nc2_0 + 1) * 32 + nh * 16 + q * 4);
    xq0[nh] = (f32x4){t0.x, t0.y, t0.z, t0.w};
    xq1[nh] = (f32x4){t1.x, t1.y, t1.z, t1.w};
  }

  for (int it2 = 0; it2 < CPB / 2; ++it2) {
    RBF_STEP(nc2_0 + it2 * 2, xb0, xq0);
    RBF_STEP(nc2_0 + it2 * 2 + 1, xb1, xq1);
  }

  if (hit) {
#pragma unroll
    for (int mi = 0; mi < 4; ++mi)
#pragma unroll
      for (int r = 0; r < 4; ++r) {
        int m = mb + mi * 16 + q * 4 + r;
        atomicAdd(&out[m * 16 + c], oacc[mi][r]);
      }
  }
}

extern "C" void kernel_launch(void* const* d_in, const int* in_sizes, int n_in,
                              void* d_out, int out_size, void* d_ws, size_t ws_size,
                              hipStream_t stream) {
  const float* z = (const float*)d_in[0];
  const float* dataset = (const float*)d_in[1];
  const float* alpha = (const float*)d_in[2];
  float* out = (float*)d_out;
  char* ws = (char*)d_ws;

  bf16x8* xph = (bf16x8*)ws;                       // 12,845,056
  bf16x8* xpl = xph + NC16 * 2 * 64;               // -> 25,690,112
  bf16x8* aph = (bf16x8*)(ws + 25690112);          // 3,211,264
  bf16x8* apl = aph + NC32 * 64;                   // -> 32,112,640
  bf16x8* zph = (bf16x8*)(ws + 32112640);          // 262,144
  bf16x8* zpl = zph + MC16 * 2 * 64;               // -> 32,636,928
  float* xs2 = (float*)(ws + 32636928);            // NPAD floats -> 33,038,336
  float* zs2 = (float*)(ws + 33038336);            // 2048 floats -> 33,046,528

  hipMemsetAsync(d_out, 0, (size_t)out_size * sizeof(float), stream);
  int prep_waves = NC16 + MC16 + NC32;             // 9536
  prep_all<<<dim3((prep_waves + 3) / 4), dim3(256), 0, stream>>>(
      z, dataset, alpha, xph, xpl, zph, zpl, aph, apl, xs2, zs2);
  rbf_main<<<dim3(GRID), dim3(256), 0, stream>>>(
      xph, xpl, aph, apl, zph, zpl, xs2, zs2, out);
}